// Round 10
// baseline (30.743 us; speedup 1.0000x reference)
//
#include <hip/hip_runtime.h>
#include <math.h>

// Biquad peaking EQ over [B=8, C=2, T=1200000] f32.
// Round 10: NO input staging — per-lane register rows, direct from HBM.
//  - Lane i owns samples [g0+32i, g0+32i+32) = exactly one 128-B line,
//    loaded as 8 x f32x4 at wave start. Loads feed the biquad chain through
//    the compiler's counted vmcnt waits: no LDS stage, no fences, no
//    ping-pong, nothing between HBM and the FMA chain.
//  - Neighbor tail x[n-1],x[n-2] = lane i-1's r[7].w/.z via 2 __shfl_up
//    (was an LDS cross-lane read).
//  - LDS used ONLY for the output transpose: biquad writes y row i
//    (b128, stride-36 rows = minimal banking), store loop reads column
//    slices + applies the truncated-series correction, coalesced float4 out.
//  - Non-persistent grid: 2500 blocks x 4 waves, ONE segment per wave.
//    Hardware block dispatch backfills CUs -> balance with no tail logic,
//    and consecutive blocks naturally overlap load phase with compute phase.
//  - Truncated-series entry states (4 independent shfl_up pairs,
//    ||M^32||~0.1, truncation ~4e-3): validated r8/r9, absmax 0.031.
// Warm-up: lanes 0-3 (128 samples) compute but don't store; segment 0 of
// each channel has exact zero prehistory. NO atomics (round-6 lesson:
// one hot atomic line across 8 XCDs = 170us serial floor).

typedef float f32x4 __attribute__((ext_vector_type(4)));

#define T_LEN 1200000
#define NCH   16
#define L     32
#define NR    64
#define NWARM 4
#define OUT_ROWS (NR - NWARM)           // 60
#define OUT_PER_SEG (OUT_ROWS * L)      // 1920
#define SEGS_PER_CH (T_LEN / OUT_PER_SEG)   // 625 (exact)
#define NSEG (SEGS_PER_CH * NCH)        // 10000
#define WPB 4
#define NBLOCKS (NSEG / WPB)            // 2500 (exact)
#define RSTRIDE 36                      // words per row -> minimal b128 banking
#define WAVE_LDS (NR * RSTRIDE)         // 2304 words = 9216 B per wave

struct Params {
    float b0, b1, b2, a1, a2;
    float lnr, theta, inv_sinth;
    float C[3][4];                      // M^32, M^64, M^96 row-major
};

__global__ __launch_bounds__(256, 4) void eq_kernel(const float* __restrict__ x,
                                                    float* __restrict__ y, Params P)
{
    __shared__ __align__(16) float lds[WPB * WAVE_LDS];   // 36864 B -> 4 blocks/CU
    const int lane = threadIdx.x & 63;
    const int wid  = threadIdx.x >> 6;
    float* ys = lds + wid * WAVE_LDS;

    const int s  = blockIdx.x * WPB + wid;        // 0..9999, one segment per wave
    const int ch = s / SEGS_PER_CH;
    const int si = s - ch * SEGS_PER_CH;
    const float* __restrict__ xc = x + (size_t)ch * T_LEN;
    float*       __restrict__ yc = y + (size_t)ch * T_LEN;
    const int g0 = si * OUT_PER_SEG - NWARM * L;  // -128 only for si == 0

    // ---- per-lane correction tables: t0 = (lane*4)&31, need phi(t0-1..t0+3)
    float c1r[4], c2r[4];
    {
        const int t0 = (lane << 2) & 31;
        float ph[5];
        #pragma unroll
        for (int k = 0; k < 5; ++k) {
            int t = t0 - 1 + k;
            ph[k] = (t < 0) ? 0.f
                            : expf(t * P.lnr) * sinf((t + 1) * P.theta) * P.inv_sinth;
        }
        #pragma unroll
        for (int k = 0; k < 4; ++k) {
            c1r[k] = fmaf(-P.a1, ph[k + 1], -P.a2 * ph[k]);  // resp. to y[-1]=1
            c2r[k] = -P.a2 * ph[k + 1];                      // resp. to y[-2]=1
        }
    }

    // ---- direct per-lane loads: lane's 32 samples = one 128-B line ----
    f32x4 r[8];
    {
        const int gl = g0 + (lane << 5);
        #pragma unroll
        for (int k = 0; k < 8; ++k) {
            int g = gl + (k << 2);                // multiple of 4; T_LEN % 4 == 0
            f32x4 v = {0.f, 0.f, 0.f, 0.f};
            if (g >= 0 && g < T_LEN) v = *(const f32x4*)(xc + g);
            r[k] = v;
        }
    }

    // neighbor tail from lane i-1's registers (was an LDS read)
    float x1 = __shfl_up(r[7].w, 1);
    float x2 = __shfl_up(r[7].z, 1);
    if (lane == 0) { x1 = 0.f; x2 = 0.f; }        // prehistory: exact for si==0,
                                                  // warm-up truncation otherwise
    // ---- zero-state biquad over own row, y -> LDS row (b128) ----
    float v1 = 0.f, v2 = 0.f;
    const int base = lane * RSTRIDE;
    #pragma unroll
    for (int b = 0; b < 8; ++b) {
        f32x4 xv = r[b];
        f32x4 yv;
        #pragma unroll
        for (int k = 0; k < 4; ++k) {
            float xk = xv[k];
            float f  = fmaf(P.b0, xk, fmaf(P.b1, x1, P.b2 * x2));
            float t2 = fmaf(-P.a2, v2, f);
            float yk = fmaf(-P.a1, v1, t2);
            v2 = v1; v1 = yk;
            x2 = x1; x1 = xk;
            yv[k] = yk;
        }
        *(f32x4*)&ys[base + (b << 2)] = yv;
    }

    // ---- entry state of row `lane` via truncated series (indep. shuffles):
    // e = v_{-1} + M32*v_{-2} + M64*v_{-3} + M96*v_{-4}
    float q11 = __shfl_up(v1, 1), q21 = __shfl_up(v2, 1);
    float q12 = __shfl_up(v1, 2), q22 = __shfl_up(v2, 2);
    float q13 = __shfl_up(v1, 3), q23 = __shfl_up(v2, 3);
    float q14 = __shfl_up(v1, 4), q24 = __shfl_up(v2, 4);
    if (lane < 1) { q11 = 0.f; q21 = 0.f; }
    if (lane < 2) { q12 = 0.f; q22 = 0.f; }
    if (lane < 3) { q13 = 0.f; q23 = 0.f; }
    if (lane < 4) { q14 = 0.f; q24 = 0.f; }
    float e1 = q11, e2 = q21;
    e1 = fmaf(P.C[0][0], q12, fmaf(P.C[0][1], q22, e1));
    e2 = fmaf(P.C[0][2], q12, fmaf(P.C[0][3], q22, e2));
    e1 = fmaf(P.C[1][0], q13, fmaf(P.C[1][1], q23, e1));
    e2 = fmaf(P.C[1][2], q13, fmaf(P.C[1][3], q23, e2));
    e1 = fmaf(P.C[2][0], q14, fmaf(P.C[2][1], q24, e1));
    e2 = fmaf(P.C[2][2], q14, fmaf(P.C[2][3], q24, e2));

    // ---- store rows 4..63 with fused correction: coalesced float4 ----
    // (cross-lane LDS RAW vs the y-writes above: same-array variable-index
    //  accesses -> may-alias -> compiler preserves order; same-wave LDS is
    //  in-order in hardware. Proven across rounds 5-9.)
    const int j0 = (lane << 2) & 31;
    #pragma unroll
    for (int it = 0; it < 8; ++it) {
        int vo = (it << 6) + lane;
        int row = NWARM + (it << 3) + (lane >> 3);
        row = row > 63 ? 63 : row;               // clamp for shfl on tail lanes
        float al = __shfl(e1, row);
        float be = __shfl(e2, row);
        if (vo < OUT_PER_SEG / 4) {
            f32x4 yv = *(const f32x4*)&ys[row * RSTRIDE + j0];
            f32x4 o;
            #pragma unroll
            for (int k = 0; k < 4; ++k)
                o[k] = fmaf(al, c1r[k], fmaf(be, c2r[k], yv[k]));
            int q = (vo << 2) + NWARM * L;
            *(f32x4*)(yc + g0 + q) = o;          // g0+q in [si*1920, si*1920+1920)
        }
    }
}

extern "C" void kernel_launch(void* const* d_in, const int* in_sizes, int n_in,
                              void* d_out, int out_size, void* d_ws, size_t ws_size,
                              hipStream_t stream) {
    const float* x = (const float*)d_in[0];
    float* y = (float*)d_out;

    // torchaudio peaking-EQ coefficients (double, then cast — matches ref)
    double w0    = 2.0 * M_PI * 1000.0 / 44100.0;
    double A     = exp(6.0 / 40.0 * log(10.0));
    double al    = sin(w0) / (2.0 * 0.707);
    double b0 = 1.0 + al * A;
    double b1 = -2.0 * cos(w0);
    double b2 = 1.0 - al * A;
    double a0 = 1.0 + al / A;
    double a1 = -2.0 * cos(w0);
    double a2 = 1.0 - al / A;
    b0 /= a0; b1 /= a0; b2 /= a0; a1 /= a0; a2 /= a0;

    Params P;
    P.b0 = (float)b0; P.b1 = (float)b1; P.b2 = (float)b2;
    P.a1 = (float)a1; P.a2 = (float)a2;

    double r     = sqrt(a2);
    double theta = acos(-a1 / (2.0 * r));
    P.lnr = (float)log(r);
    P.theta = (float)theta;
    P.inv_sinth = (float)(1.0 / sin(theta));

    // M^32 via repeated squaring; then M^64, M^96
    double m00 = -a1, m01 = -a2, m10 = 1.0, m11 = 0.0;
    for (int s = 0; s < 5; ++s) {
        double t00 = m00 * m00 + m01 * m10;
        double t01 = m00 * m01 + m01 * m11;
        double t10 = m10 * m00 + m11 * m10;
        double t11 = m10 * m01 + m11 * m11;
        m00 = t00; m01 = t01; m10 = t10; m11 = t11;
    }
    double p00 = m00, p01 = m01, p10 = m10, p11 = m11;    // M^32
    for (int k = 0; k < 3; ++k) {
        P.C[k][0] = (float)p00; P.C[k][1] = (float)p01;
        P.C[k][2] = (float)p10; P.C[k][3] = (float)p11;
        double t00 = p00 * m00 + p01 * m10;               // * M^32
        double t01 = p00 * m01 + p01 * m11;
        double t10 = p10 * m00 + p11 * m10;
        double t11 = p10 * m01 + p11 * m11;
        p00 = t00; p01 = t01; p10 = t10; p11 = t11;
    }

    eq_kernel<<<NBLOCKS, 256, 0, stream>>>(x, y, P);
}